// Round 9
// baseline (421.692 us; speedup 1.0000x reference)
//
#include <hip/hip_runtime.h>
#include <hip/hip_bf16.h>

#define WPB 4   // waves per block (256 threads)
#define TILE 16 // node rows staged per block iteration
#define SUBB 8  // sub-buckets per bucket (XCD-affine via blockIdx&7)
#define BCAP 896// capacity per (bucket, sub-bucket) cell; mean 640, z>10 margin

typedef unsigned short ushort_t;
typedef unsigned int uint_t;

__device__ __forceinline__ float silu_f(float x) {
  return x * __builtin_amdgcn_rcpf(1.0f + __expf(-x));
}
__device__ __forceinline__ int rfl(int x) { return __builtin_amdgcn_readfirstlane(x); }
__device__ __forceinline__ float readlane_f(float v, int l) {
  return __int_as_float(__builtin_amdgcn_readlane(__float_as_int(v), l));
}
// f32 -> bf16 round-to-nearest-even
__device__ __forceinline__ ushort_t f2bf(float f) {
  uint_t u = __float_as_uint(f);
  u += 0x7FFFu + ((u >> 16) & 1u);
  return (ushort_t)(u >> 16);
}
__device__ __forceinline__ float bf2f(ushort_t b) {
  return __uint_as_float(((uint_t)b) << 16);
}

// ---------------------------------------------------------------------------
// Encode directly into d_out (planar): out[0..N*32) = h_s, out[N*32..) = h_v
// ---------------------------------------------------------------------------
__global__ void encode_kernel(const float* __restrict__ redshift,
                              const float* __restrict__ shapes,
                              const float* __restrict__ enc_s_w,
                              const float* __restrict__ enc_s_b,
                              const float* __restrict__ enc_v_w,
                              float* __restrict__ hout, int N_) {
  int tid = blockIdx.x * blockDim.x + threadIdx.x;
  int n = tid >> 5;
  int j = tid & 31;
  if (n >= N_) return;
  float r = redshift[n];
  float hs = fmaxf(fmaf(r, enc_s_w[j], enc_s_b[j]), 0.0f);
  float x0 = shapes[n * 2 + 0];
  float x1 = shapes[n * 2 + 1];
  float hv = fmaf(x0, enc_v_w[j * 2 + 0], x1 * enc_v_w[j * 2 + 1]);
  hout[(size_t)n * 32 + j] = hs;
  hout[(size_t)N_ * 32 + (size_t)n * 32 + j] = hv;
}

__global__ void zero_kernel(int* __restrict__ p, int n) {
  int i = blockIdx.x * blockDim.x + threadIdx.x;
  if (i < n) p[i] = 0;
}

// ---------------------------------------------------------------------------
// Stage 1: bucket append. cell = (dst>>8)*8 | (blockIdx&7). Per-cell atomic
// cursor makes concurrent writes land in consecutive slots -> frontier 64B
// lines fill completely inside one XCD's L2 -> ~1x write amplification.
// Record: (dist f32, [s2|c2] bf16x2, src bits, dst bits)
// ---------------------------------------------------------------------------
__global__ void bucket_kernel(const int* __restrict__ ei, const float* __restrict__ pos,
                              int* __restrict__ bcnt, float4* __restrict__ bdata,
                              int E_) {
  int e = blockIdx.x * blockDim.x + threadIdx.x;
  if (e >= E_) return;
  int s = ei[e];
  int d = ei[E_ + e];
  float dx = pos[s * 2 + 0] - pos[d * 2 + 0];
  float dy = pos[s * 2 + 1] - pos[d * 2 + 1];
  float r2 = fmaf(dx, dx, dy * dy);
  float dist = sqrtf(r2) + 1e-6f;
  float c2 = 1.0f, s2 = 0.0f;
  if (r2 > 0.0f) {
    float inv = 1.0f / r2;
    c2 = (dx * dx - dy * dy) * inv;
    s2 = 2.0f * dx * dy * inv;
  }
  uint_t pk = ((uint_t)f2bf(s2) << 16) | (uint_t)f2bf(c2);
  int cell = ((d >> 8) << 3) | (blockIdx.x & (SUBB - 1));
  int slot = atomicAdd(&bcnt[cell], 1);
  bdata[(size_t)cell * BCAP + slot] =
      make_float4(dist, __uint_as_float(pk), __int_as_float(s), __int_as_float(d));
}

// ---------------------------------------------------------------------------
// Bucket totals -> exclusive scan (one block; NB <= 256).
// ---------------------------------------------------------------------------
__global__ __launch_bounds__(256) void bscan_kernel(const int* __restrict__ bcnt,
                                                    int* __restrict__ bucketBase, int NB) {
  __shared__ int wsum[4];
  int t = threadIdx.x, lane = t & 63, wid = t >> 6;
  int v = 0;
  if (t < NB) {
#pragma unroll
    for (int x = 0; x < SUBB; ++x) v += bcnt[t * SUBB + x];
  }
  int x = v;
#pragma unroll
  for (int off = 1; off < 64; off <<= 1) {
    int y = __shfl_up(x, off);
    if (lane >= off) x += y;
  }
  if (lane == 63) wsum[wid] = x;
  __syncthreads();
  if (t == 0) {
    int run = 0;
#pragma unroll
    for (int w = 0; w < 4; ++w) { int s = wsum[w]; wsum[w] = run; run += s; }
  }
  __syncthreads();
  int inc = x + wsum[wid];
  if (t < NB) bucketBase[t + 1] = inc;
  if (t == 0) bucketBase[0] = 0;
}

// ---------------------------------------------------------------------------
// Stage 2: per-bucket counting sort into final dst-sorted edata; emits deg.
// Output range per bucket is contiguous (~80KB) -> scattered writes L2-absorb.
// ---------------------------------------------------------------------------
__global__ __launch_bounds__(256) void bsort_kernel(
    const float4* __restrict__ bdata, const int* __restrict__ bcnt,
    const int* __restrict__ bucketBase, float4* __restrict__ edata,
    int* __restrict__ deg, int N_) {
  __shared__ int hist[256];
  __shared__ int offs[256];
  __shared__ int cur[256];
  int b = blockIdx.x;
  int t = threadIdx.x;
  hist[t] = 0;
  cur[t] = 0;
  __syncthreads();
  // pass 1: count dst occurrences (reads only the .w dword)
  for (int x = 0; x < SUBB; ++x) {
    int cnt = bcnt[b * SUBB + x];
    const float4* src = bdata + (size_t)(b * SUBB + x) * BCAP;
    for (int i = t; i < cnt; i += 256) {
      int d = __float_as_int(src[i].w);
      atomicAdd(&hist[d & 255], 1);
    }
  }
  __syncthreads();
  if (t == 0) {
    int run = 0;
    for (int i = 0; i < 256; ++i) { offs[i] = run; run += hist[i]; }
  }
  __syncthreads();
  int n = (b << 8) + t;
  if (n < N_) deg[n] = hist[t];
  int base = bucketBase[b];
  // pass 2: place
  for (int x = 0; x < SUBB; ++x) {
    int cnt = bcnt[b * SUBB + x];
    const float4* src = bdata + (size_t)(b * SUBB + x) * BCAP;
    for (int i = t; i < cnt; i += 256) {
      float4 r = src[i];
      int ld = __float_as_int(r.w) & 255;
      int slot = base + offs[ld] + atomicAdd(&cur[ld], 1);
      edata[slot] = r;
    }
  }
}

__global__ void pad_kernel(float4* __restrict__ edata, int E_, int N_) {
  int i = E_ + threadIdx.x;
  edata[i] = make_float4(0.f, 0.f, __int_as_float(0), __int_as_float(N_));
}

// ---------------------------------------------------------------------------
// Standalone projections (layer 0 only) + H zeroing.
//   PS[n,j]  = h_s[n]·W1[j,0:32] + h_v[n]·W1[j,64:96]   (bf16)
//   PDB[n,j] = h_s[n]·W1[j,32:64] + b1[j]               (bf16)
// ---------------------------------------------------------------------------
__global__ __launch_bounds__(256) void psd_kernel(
    const float* __restrict__ hout, const float* __restrict__ W1l,
    const float* __restrict__ b1l,
    ushort_t* __restrict__ PSh, ushort_t* __restrict__ PDBh,
    float* __restrict__ H, int N_) {
  __shared__ float wsh[99 * 64];
  __shared__ __align__(16) float hsh[TILE][64];
  int t = threadIdx.x;
  for (int i = t; i < 99 * 64; i += 256) wsh[i] = W1l[i];
  __syncthreads();
  int lane = t & 63, wib = t >> 6;
  float ws_[32], wd_[32], wv_[32];
#pragma unroll
  for (int k = 0; k < 32; ++k) {
    ws_[k] = wsh[lane * 99 + k];
    wd_[k] = wsh[lane * 99 + 32 + k];
    wv_[k] = wsh[lane * 99 + 64 + k];
  }
  float bb1 = b1l[lane];
  const int nTiles = (N_ + TILE - 1) / TILE;
  const float* hvbase = hout + (size_t)N_ * 32;
  int tt = t & 127;
  int sn = tt >> 3;        // node slot 0..15
  int sc = tt & 7;         // float4 column 0..7 within 32 floats
  for (int tile = blockIdx.x; tile < nTiles; tile += gridDim.x) {
    int base = tile * TILE;
    {
      int n = base + sn;
      const float* src = (t < 128) ? (hout + (size_t)n * 32 + sc * 4)
                                   : (hvbase + (size_t)n * 32 + sc * 4);
      float4 v = (n < N_) ? *reinterpret_cast<const float4*>(src)
                          : make_float4(0.f, 0.f, 0.f, 0.f);
      *reinterpret_cast<float4*>(&hsh[sn][(t < 128 ? 0 : 32) + sc * 4]) = v;
    }
    __syncthreads();
#pragma unroll
    for (int q = 0; q < 4; ++q) {
      int r = wib + q * 4;
      int n = base + r;
      if (n < N_) {
        const float4* ha = reinterpret_cast<const float4*>(hsh[r]);
        float ps0 = 0.f, ps1 = 0.f, ps2 = 0.f, ps3 = 0.f, pd0 = 0.f, pd1 = 0.f;
#pragma unroll
        for (int k4 = 0; k4 < 8; ++k4) {
          float4 a = ha[k4];
          float4 v = ha[8 + k4];
          int k = k4 * 4;
          ps0 = fmaf(a.x, ws_[k], ps0);     pd0 = fmaf(a.x, wd_[k], pd0);
          ps1 = fmaf(a.y, ws_[k + 1], ps1); pd1 = fmaf(a.y, wd_[k + 1], pd1);
          ps2 = fmaf(a.z, ws_[k + 2], ps2); pd0 = fmaf(a.z, wd_[k + 2], pd0);
          ps3 = fmaf(a.w, ws_[k + 3], ps3); pd1 = fmaf(a.w, wd_[k + 3], pd1);
          ps0 = fmaf(v.x, wv_[k], ps0);
          ps1 = fmaf(v.y, wv_[k + 1], ps1);
          ps2 = fmaf(v.z, wv_[k + 2], ps2);
          ps3 = fmaf(v.w, wv_[k + 3], ps3);
        }
        PSh[(size_t)n * 64 + lane] = f2bf((ps0 + ps1) + (ps2 + ps3));
        PDBh[(size_t)n * 64 + lane] = f2bf((pd0 + pd1) + bb1);
        H[(size_t)n * 64 + lane] = 0.0f;
      }
    }
    __syncthreads();
  }
}

// ---------------------------------------------------------------------------
// Edge phase: one wave per 64-edge chunk. 2-deep software pipeline: 16 PS
// gathers in flight while consuming 8 -> hides L2 latency. Segment-boundary
// PDB values prefetched a full segment ahead. Dual accumulators.
// ---------------------------------------------------------------------------
#define ISSUE(P, G)                                             \
  do {                                                          \
    int t0 = __builtin_amdgcn_readlane(sv, (G) + 0);            \
    int t1 = __builtin_amdgcn_readlane(sv, (G) + 1);            \
    int t2 = __builtin_amdgcn_readlane(sv, (G) + 2);            \
    int t3 = __builtin_amdgcn_readlane(sv, (G) + 3);            \
    int t4 = __builtin_amdgcn_readlane(sv, (G) + 4);            \
    int t5 = __builtin_amdgcn_readlane(sv, (G) + 5);            \
    int t6 = __builtin_amdgcn_readlane(sv, (G) + 6);            \
    int t7 = __builtin_amdgcn_readlane(sv, (G) + 7);            \
    P##0 = PSh[(size_t)t0 * 64 + lane];                         \
    P##1 = PSh[(size_t)t1 * 64 + lane];                         \
    P##2 = PSh[(size_t)t2 * 64 + lane];                         \
    P##3 = PSh[(size_t)t3 * 64 + lane];                         \
    P##4 = PSh[(size_t)t4 * 64 + lane];                         \
    P##5 = PSh[(size_t)t5 * 64 + lane];                         \
    P##6 = PSh[(size_t)t6 * 64 + lane];                         \
    P##7 = PSh[(size_t)t7 * 64 + lane];                         \
  } while (0)

#define FLUSH()                                                          \
  do {                                                                   \
    atomicAdd(H + (size_t)dcur * 64 + lane, acc0 + acc1);                \
    acc0 = acc1 = 0.0f;                                                  \
    dcur = dnext;                                                        \
    pdj = pdj_next;                                                      \
    bmask &= bmask - 1;                                                  \
    bnext = bmask ? (int)__builtin_ctzll(bmask) : 64;                    \
    dnext = (bnext < 64) ? __builtin_amdgcn_readlane(dv, bnext) : dcur;  \
    pdj_next = bf2f(PDBh[(size_t)dnext * 64 + lane]);                    \
  } while (0)

#define EDGE_ONE(PSV, E)                                                     \
  do {                                                                       \
    if ((E) == bnext) FLUSH();                                               \
    float psv = bf2f((ushort_t)(PSV));                                       \
    float di = readlane_f(ed.x, (E));                                        \
    uint_t pk = (uint_t)__builtin_amdgcn_readlane(__float_as_int(ed.y), (E));\
    float c2 = __uint_as_float(pk << 16);                                    \
    float s2 = __uint_as_float(pk & 0xFFFF0000u);                            \
    float pre = fmaf(wg0, di, fmaf(wg1, c2, fmaf(wg2, s2, psv + pdj)));      \
    if ((E) & 1) acc1 += silu_f(pre); else acc0 += silu_f(pre);              \
  } while (0)

#define CONSUME(P, G)                                            \
  do {                                                           \
    EDGE_ONE(P##0, (G) + 0); EDGE_ONE(P##1, (G) + 1);            \
    EDGE_ONE(P##2, (G) + 2); EDGE_ONE(P##3, (G) + 3);            \
    EDGE_ONE(P##4, (G) + 4); EDGE_ONE(P##5, (G) + 5);            \
    EDGE_ONE(P##6, (G) + 6); EDGE_ONE(P##7, (G) + 7);            \
  } while (0)

__global__ __launch_bounds__(256) void edge_kernel(
    const ushort_t* __restrict__ PSh, const ushort_t* __restrict__ PDBh,
    const float4* __restrict__ edata,
    const float* __restrict__ W1l, float* __restrict__ H, int nchunk) {
  int lane = threadIdx.x & 63, wib = threadIdx.x >> 6;
  int chunk = blockIdx.x * WPB + wib;
  if (chunk >= nchunk) return;
  int base = chunk << 6;
  float wg0 = W1l[lane * 99 + 96];
  float wg1 = W1l[lane * 99 + 97];
  float wg2 = W1l[lane * 99 + 98];
  float4 ed = edata[base + lane];  // x=dist, y=[s2|c2]bf16, z=src, w=dst
  int sv = __float_as_int(ed.z);
  int dv = __float_as_int(ed.w);
  int dprev = __shfl_up(dv, 1);
  unsigned long long bmask = __ballot(dv != dprev) & ~1ull;
  int dcur = rfl(dv);
  float pdj = bf2f(PDBh[(size_t)dcur * 64 + lane]);
  int bnext = bmask ? (int)__builtin_ctzll(bmask) : 64;
  int dnext = (bnext < 64) ? __builtin_amdgcn_readlane(dv, bnext) : dcur;
  float pdj_next = bf2f(PDBh[(size_t)dnext * 64 + lane]);
  float acc0 = 0.0f, acc1 = 0.0f;
  uint_t pA0, pA1, pA2, pA3, pA4, pA5, pA6, pA7;
  uint_t pB0, pB1, pB2, pB3, pB4, pB5, pB6, pB7;
  ISSUE(pA, 0);
  ISSUE(pB, 8);
  CONSUME(pA, 0);
  ISSUE(pA, 16);
  CONSUME(pB, 8);
  ISSUE(pB, 24);
  CONSUME(pA, 16);
  ISSUE(pA, 32);
  CONSUME(pB, 24);
  ISSUE(pB, 40);
  CONSUME(pA, 32);
  ISSUE(pA, 48);
  CONSUME(pB, 40);
  ISSUE(pB, 56);
  CONSUME(pA, 48);
  CONSUME(pB, 56);
  atomicAdd(H + (size_t)dcur * 64 + lane, acc0 + acc1);
}

// ---------------------------------------------------------------------------
// Fused node update + next-layer projection:
//   hnew[n] = h[n] + W2.H[n] + deg(n)*b2   -> hout (and kept in LDS)
//   PS/PDB(next layer) from hnew; H zeroed for next layer.
// ---------------------------------------------------------------------------
__global__ __launch_bounds__(256) void updproj_kernel(
    float* __restrict__ hout, float* __restrict__ H,
    const int* __restrict__ deg,
    const float* __restrict__ W2l, const float* __restrict__ b2l,
    const float* __restrict__ W1n, const float* __restrict__ b1n,
    ushort_t* __restrict__ PSh, ushort_t* __restrict__ PDBh, int N_) {
  __shared__ float w2sh[64 * 65];
  __shared__ float wsh[99 * 64];
  __shared__ __align__(16) float Hsh[TILE][64];
  int t = threadIdx.x;
  for (int i = t; i < 64 * 64; i += 256) w2sh[(i >> 6) * 65 + (i & 63)] = W2l[i];
  for (int i = t; i < 99 * 64; i += 256) wsh[i] = W1n[i];
  __syncthreads();
  int lane = t & 63, wib = t >> 6;
  float w2[64];
#pragma unroll
  for (int k = 0; k < 64; ++k) w2[k] = w2sh[lane * 65 + k];
  float ws_[32], wd_[32], wv_[32];
#pragma unroll
  for (int k = 0; k < 32; ++k) {
    ws_[k] = wsh[lane * 99 + k];
    wd_[k] = wsh[lane * 99 + 32 + k];
    wv_[k] = wsh[lane * 99 + 64 + k];
  }
  float bb2 = b2l[lane];
  float bb1 = b1n[lane];
  const int nTiles = (N_ + TILE - 1) / TILE;
  size_t plane = (size_t)(lane >> 5) * ((size_t)N_ * 32);
  int sn = t >> 4;   // node slot 0..15
  int sc = t & 15;   // float4 column 0..15 within 64 floats
  for (int tile = blockIdx.x; tile < nTiles; tile += gridDim.x) {
    int base = tile * TILE;
    {
      int n = base + sn;
      float4 v = (n < N_) ? *reinterpret_cast<const float4*>(H + (size_t)n * 64 + sc * 4)
                          : make_float4(0.f, 0.f, 0.f, 0.f);
      *reinterpret_cast<float4*>(&Hsh[sn][sc * 4]) = v;
    }
    __syncthreads();
#pragma unroll
    for (int q = 0; q < 4; ++q) {
      int r = wib + q * 4;
      int n = base + r;
      if (n < N_) {
        const float4* hm = reinterpret_cast<const float4*>(Hsh[r]);
        float o0 = 0.f, o1 = 0.f;
#pragma unroll
        for (int k4 = 0; k4 < 16; k4 += 2) {
          float4 m0 = hm[k4];
          float4 m1 = hm[k4 + 1];
          o0 = fmaf(m0.x, w2[k4 * 4 + 0], o0);
          o0 = fmaf(m0.y, w2[k4 * 4 + 1], o0);
          o0 = fmaf(m0.z, w2[k4 * 4 + 2], o0);
          o0 = fmaf(m0.w, w2[k4 * 4 + 3], o0);
          o1 = fmaf(m1.x, w2[k4 * 4 + 4], o1);
          o1 = fmaf(m1.y, w2[k4 * 4 + 5], o1);
          o1 = fmaf(m1.z, w2[k4 * 4 + 6], o1);
          o1 = fmaf(m1.w, w2[k4 * 4 + 7], o1);
        }
        float degf = (float)deg[n];
        size_t idx = plane + (size_t)n * 32 + (lane & 31);
        float hnew = hout[idx] + (o0 + o1) + degf * bb2;
        hout[idx] = hnew;
        Hsh[r][lane] = hnew;
        asm volatile("s_waitcnt lgkmcnt(0)" ::: "memory");
        const float4* ha = reinterpret_cast<const float4*>(Hsh[r]);
        float ps0 = 0.f, ps1 = 0.f, ps2 = 0.f, ps3 = 0.f, pd0 = 0.f, pd1 = 0.f;
#pragma unroll
        for (int k4 = 0; k4 < 8; ++k4) {
          float4 a = ha[k4];
          float4 v = ha[8 + k4];
          int k = k4 * 4;
          ps0 = fmaf(a.x, ws_[k], ps0);     pd0 = fmaf(a.x, wd_[k], pd0);
          ps1 = fmaf(a.y, ws_[k + 1], ps1); pd1 = fmaf(a.y, wd_[k + 1], pd1);
          ps2 = fmaf(a.z, ws_[k + 2], ps2); pd0 = fmaf(a.z, wd_[k + 2], pd0);
          ps3 = fmaf(a.w, ws_[k + 3], ps3); pd1 = fmaf(a.w, wd_[k + 3], pd1);
          ps0 = fmaf(v.x, wv_[k], ps0);
          ps1 = fmaf(v.y, wv_[k + 1], ps1);
          ps2 = fmaf(v.z, wv_[k + 2], ps2);
          ps3 = fmaf(v.w, wv_[k + 3], ps3);
        }
        PSh[(size_t)n * 64 + lane] = f2bf((ps0 + ps1) + (ps2 + ps3));
        PDBh[(size_t)n * 64 + lane] = f2bf((pd0 + pd1) + bb1);
        H[(size_t)n * 64 + lane] = 0.0f;
      }
    }
    __syncthreads();
  }
}

// ---------------------------------------------------------------------------
// Final node update (last layer): h[n,:] += W2 . H[n,:] + deg(n)*b2
// ---------------------------------------------------------------------------
__global__ __launch_bounds__(256) void out_kernel(
    float* __restrict__ hout, const float* __restrict__ H,
    const int* __restrict__ deg,
    const float* __restrict__ W2l, const float* __restrict__ b2l, int N_) {
  __shared__ float w2sh[64 * 65];
  __shared__ __align__(16) float Hsh[TILE][64];
  int t = threadIdx.x;
  for (int i = t; i < 64 * 64; i += 256) w2sh[(i >> 6) * 65 + (i & 63)] = W2l[i];
  __syncthreads();
  int lane = t & 63, wib = t >> 6;
  float w2[64];
#pragma unroll
  for (int k = 0; k < 64; ++k) w2[k] = w2sh[lane * 65 + k];
  float bb2 = b2l[lane];
  const int nTiles = (N_ + TILE - 1) / TILE;
  size_t plane = (size_t)(lane >> 5) * ((size_t)N_ * 32);
  int sn = t >> 4;
  int sc = t & 15;
  for (int tile = blockIdx.x; tile < nTiles; tile += gridDim.x) {
    int base = tile * TILE;
    {
      int n = base + sn;
      float4 v = (n < N_) ? *reinterpret_cast<const float4*>(H + (size_t)n * 64 + sc * 4)
                          : make_float4(0.f, 0.f, 0.f, 0.f);
      *reinterpret_cast<float4*>(&Hsh[sn][sc * 4]) = v;
    }
    __syncthreads();
#pragma unroll
    for (int q = 0; q < 4; ++q) {
      int r = wib + q * 4;
      int n = base + r;
      if (n < N_) {
        const float4* hm = reinterpret_cast<const float4*>(Hsh[r]);
        float o0 = 0.f, o1 = 0.f;
#pragma unroll
        for (int k4 = 0; k4 < 16; k4 += 2) {
          float4 m0 = hm[k4];
          float4 m1 = hm[k4 + 1];
          o0 = fmaf(m0.x, w2[k4 * 4 + 0], o0);
          o0 = fmaf(m0.y, w2[k4 * 4 + 1], o0);
          o0 = fmaf(m0.z, w2[k4 * 4 + 2], o0);
          o0 = fmaf(m0.w, w2[k4 * 4 + 3], o0);
          o1 = fmaf(m1.x, w2[k4 * 4 + 4], o1);
          o1 = fmaf(m1.y, w2[k4 * 4 + 5], o1);
          o1 = fmaf(m1.z, w2[k4 * 4 + 6], o1);
          o1 = fmaf(m1.w, w2[k4 * 4 + 7], o1);
        }
        float degf = (float)deg[n];
        size_t idx = plane + (size_t)n * 32 + (lane & 31);
        hout[idx] += (o0 + o1) + degf * bb2;
      }
    }
    __syncthreads();
  }
}

extern "C" void kernel_launch(void* const* d_in, const int* in_sizes, int n_in,
                              void* d_out, int out_size, void* d_ws, size_t ws_size,
                              hipStream_t stream) {
  const float* pos      = (const float*)d_in[0];
  const float* redshift = (const float*)d_in[1];
  const float* shapes   = (const float*)d_in[2];
  const int*   ei       = (const int*)d_in[3];
  const float* enc_s_w  = (const float*)d_in[4];
  const float* enc_s_b  = (const float*)d_in[5];
  const float* enc_v_w  = (const float*)d_in[6];
  const float* W1       = (const float*)d_in[7];
  const float* b1       = (const float*)d_in[8];
  const float* W2       = (const float*)d_in[9];
  const float* b2       = (const float*)d_in[10];

  const int N_ = in_sizes[1];      // 50000
  const int E_ = in_sizes[3] / 2;  // 1000000
  const int nchunk = (E_ + 63) / 64;
  const int padE = nchunk * 64;
  const int NB = (N_ + 255) >> 8;  // 196 buckets of 256 nodes

  // Workspace (~42 MB). bdata (stage-1 buckets) ALIASES the H/PSh/PDBh
  // region: bsort finishes reading bdata before psd first writes H/PSh/PDBh.
  float4* edata = (float4*)d_ws;                            // padE * 16B
  char*   regionA = (char*)(edata + padE);
  float*    H    = (float*)regionA;                         // (N+1)*64 f32
  ushort_t* PSh  = (ushort_t*)(H + (size_t)(N_ + 1) * 64);  // N*64 bf16
  ushort_t* PDBh = PSh + (size_t)N_ * 64;                   // (N+1)*64 bf16
  float4* bdata  = (float4*)regionA;                        // NB*SUBB*BCAP*16B (alias)
  size_t szH = (size_t)(N_ + 1) * 64 * 4 + (size_t)N_ * 64 * 2 + (size_t)(N_ + 1) * 64 * 2;
  size_t szB = (size_t)NB * SUBB * BCAP * 16;
  size_t regA = (szH > szB ? szH : szB);
  regA = (regA + 15) & ~(size_t)15;
  int* deg        = (int*)(regionA + regA);                 // N
  int* bcnt       = deg + N_;                               // NB*SUBB
  int* bucketBase = bcnt + NB * SUBB;                       // NB+1

  float* hout = (float*)d_out;  // planar h lives in d_out

  encode_kernel<<<dim3((N_ * 32 + 255) / 256), dim3(256), 0, stream>>>(
      redshift, shapes, enc_s_w, enc_s_b, enc_v_w, hout, N_);

  // CSR build via two-stage bucket sort (once; replaces deg+scan+scatter)
  zero_kernel<<<dim3((NB * SUBB + 255) / 256), dim3(256), 0, stream>>>(bcnt, NB * SUBB);
  bucket_kernel<<<dim3((E_ + 255) / 256), dim3(256), 0, stream>>>(
      ei, pos, bcnt, bdata, E_);
  bscan_kernel<<<dim3(1), dim3(256), 0, stream>>>(bcnt, bucketBase, NB);
  bsort_kernel<<<dim3(NB), dim3(256), 0, stream>>>(
      bdata, bcnt, bucketBase, edata, deg, N_);
  if (padE > E_)
    pad_kernel<<<dim3(1), dim3(padE - E_), 0, stream>>>(edata, E_, N_);

  const int edgeBlocks = (nchunk + WPB - 1) / WPB;

  // layer 0 projections
  psd_kernel<<<dim3(1024), dim3(256), 0, stream>>>(
      hout, W1, b1, PSh, PDBh, H, N_);

  for (int l = 0; l < 3; ++l) {
    const float* W2l = W2 + (size_t)l * 64 * 64;
    const float* b2l = b2 + (size_t)l * 64;
    edge_kernel<<<dim3(edgeBlocks), dim3(256), 0, stream>>>(
        PSh, PDBh, edata, W1 + (size_t)l * 64 * 99, H, nchunk);
    if (l < 2) {
      updproj_kernel<<<dim3(1024), dim3(256), 0, stream>>>(
          hout, H, deg, W2l, b2l,
          W1 + (size_t)(l + 1) * 64 * 99, b1 + (size_t)(l + 1) * 64,
          PSh, PDBh, N_);
    } else {
      out_kernel<<<dim3(1024), dim3(256), 0, stream>>>(
          hout, H, deg, W2l, b2l, N_);
    }
  }
}

// Round 10
// 321.577 us; speedup vs baseline: 1.3113x; 1.3113x over previous
//
#include <hip/hip_runtime.h>
#include <hip/hip_bf16.h>

#define WPB 4   // waves per block (256 threads)
#define TILE 16 // node rows staged per block iteration

typedef unsigned short ushort_t;
typedef unsigned int uint_t;

__device__ __forceinline__ float silu_f(float x) {
  return x * __builtin_amdgcn_rcpf(1.0f + __expf(-x));
}
__device__ __forceinline__ int rfl(int x) { return __builtin_amdgcn_readfirstlane(x); }
__device__ __forceinline__ float readlane_f(float v, int l) {
  return __int_as_float(__builtin_amdgcn_readlane(__float_as_int(v), l));
}
// f32 -> bf16 round-to-nearest-even
__device__ __forceinline__ ushort_t f2bf(float f) {
  uint_t u = __float_as_uint(f);
  u += 0x7FFFu + ((u >> 16) & 1u);
  return (ushort_t)(u >> 16);
}
__device__ __forceinline__ float bf2f(ushort_t b) {
  return __uint_as_float(((uint_t)b) << 16);
}

__global__ void zero_kernel(int* __restrict__ p, int n) {
  int i = blockIdx.x * blockDim.x + threadIdx.x;
  if (i < n) p[i] = 0;
}

// ---------------------------------------------------------------------------
// CSR build (once): degree, hierarchical scan, ONE fused scatter pass.
// (Round-9's bucket-sort alternative measured 3.4x slower: hot-cursor atomic
//  contention. Single scatter's ~52us line-touch toll is the empirical floor.)
// ---------------------------------------------------------------------------
__global__ void deg_kernel(const int* __restrict__ ei, int* __restrict__ deg, int E_) {
  int e = blockIdx.x * blockDim.x + threadIdx.x;
  if (e < E_) atomicAdd(&deg[ei[E_ + e]], 1);
}

__global__ __launch_bounds__(1024) void scanA_kernel(const int* __restrict__ deg,
                                                     int* __restrict__ rowptr,
                                                     int* __restrict__ bsum, int n) {
  __shared__ int wsum[16];
  int t = threadIdx.x, lane = t & 63, wid = t >> 6;
  int i = blockIdx.x * 1024 + t;
  int v = (i < n) ? deg[i] : 0;
  int x = v;
#pragma unroll
  for (int off = 1; off < 64; off <<= 1) {
    int y = __shfl_up(x, off);
    if (lane >= off) x += y;
  }
  if (lane == 63) wsum[wid] = x;
  __syncthreads();
  if (t == 0) {
    int run = 0;
#pragma unroll
    for (int w = 0; w < 16; ++w) { int s = wsum[w]; wsum[w] = run; run += s; }
  }
  __syncthreads();
  int inc = x + wsum[wid];
  if (i < n) rowptr[i + 1] = inc;  // inclusive within block
  if (t == 1023) bsum[blockIdx.x] = inc;
}

__global__ __launch_bounds__(1024) void scanB_kernel(int* __restrict__ bsum, int nb) {
  __shared__ int wsum[16];
  int t = threadIdx.x, lane = t & 63, wid = t >> 6;
  int v = (t < nb) ? bsum[t] : 0;
  int x = v;
#pragma unroll
  for (int off = 1; off < 64; off <<= 1) {
    int y = __shfl_up(x, off);
    if (lane >= off) x += y;
  }
  if (lane == 63) wsum[wid] = x;
  __syncthreads();
  if (t == 0) {
    int run = 0;
#pragma unroll
    for (int w = 0; w < 16; ++w) { int s = wsum[w]; wsum[w] = run; run += s; }
  }
  __syncthreads();
  if (t < nb) bsum[t] = x - v + wsum[wid];  // exclusive
}

__global__ void scanC_kernel(int* __restrict__ rowptr, const int* __restrict__ bsum, int n) {
  int i = blockIdx.x * blockDim.x + threadIdx.x;
  if (i == 0) rowptr[0] = 0;
  if (i < n) rowptr[i + 1] += bsum[i >> 10];
}

// Fused scatter, ONE 16B record per edge:
//   edata = (dist f32, [s2|c2] bf16x2, src bits, dst bits)
__global__ void scatter_kernel(const int* __restrict__ ei, const float* __restrict__ pos,
                               const int* __restrict__ rowptr, int* __restrict__ cursor,
                               float4* __restrict__ edata,
                               int E_, int padE, int N_) {
  int e = blockIdx.x * blockDim.x + threadIdx.x;
  if (e >= padE) return;
  if (e >= E_) {  // sentinel slots -> pad row N_ of H/PDB
    edata[e] = make_float4(0.f, 0.f, __int_as_float(0), __int_as_float(N_));
    return;
  }
  int s = ei[e];
  int d = ei[E_ + e];
  int idx = rowptr[d] + atomicAdd(&cursor[d], 1);
  float dx = pos[s * 2 + 0] - pos[d * 2 + 0];
  float dy = pos[s * 2 + 1] - pos[d * 2 + 1];
  float r2 = fmaf(dx, dx, dy * dy);
  float dist = sqrtf(r2) + 1e-6f;
  float c2 = 1.0f, s2 = 0.0f;
  if (r2 > 0.0f) {
    float inv = 1.0f / r2;
    c2 = (dx * dx - dy * dy) * inv;
    s2 = 2.0f * dx * dy * inv;
  }
  uint_t pk = ((uint_t)f2bf(s2) << 16) | (uint_t)f2bf(c2);
  edata[idx] = make_float4(dist, __uint_as_float(pk),
                           __int_as_float(s), __int_as_float(d));
}

// ---------------------------------------------------------------------------
// Fused encode + layer-0 projections + H zeroing. Computes h from
// redshift/shapes inline during tile staging (writes hout once), then:
//   PS[n,j]  = h_s[n]·W1[j,0:32] + h_v[n]·W1[j,64:96]   (bf16)
//   PDB[n,j] = h_s[n]·W1[j,32:64] + b1[j]               (bf16)
// ---------------------------------------------------------------------------
__global__ __launch_bounds__(256) void encpsd_kernel(
    const float* __restrict__ redshift, const float* __restrict__ shapes,
    const float* __restrict__ enc_s_w, const float* __restrict__ enc_s_b,
    const float* __restrict__ enc_v_w,
    float* __restrict__ hout, const float* __restrict__ W1l,
    const float* __restrict__ b1l,
    ushort_t* __restrict__ PSh, ushort_t* __restrict__ PDBh,
    float* __restrict__ H, int N_) {
  __shared__ float wsh[99 * 64];
  __shared__ float esw[32], esb[32], evw[64];
  __shared__ __align__(16) float hsh[TILE][64];
  int t = threadIdx.x;
  for (int i = t; i < 99 * 64; i += 256) wsh[i] = W1l[i];
  if (t < 32) { esw[t] = enc_s_w[t]; esb[t] = enc_s_b[t]; }
  else if (t < 96) { evw[t - 32] = enc_v_w[t - 32]; }
  __syncthreads();
  int lane = t & 63, wib = t >> 6;
  float ws_[32], wd_[32], wv_[32];
#pragma unroll
  for (int k = 0; k < 32; ++k) {
    ws_[k] = wsh[lane * 99 + k];
    wd_[k] = wsh[lane * 99 + 32 + k];
    wv_[k] = wsh[lane * 99 + 64 + k];
  }
  float bb1 = b1l[lane];
  const int nTiles = (N_ + TILE - 1) / TILE;
  float* hvbase = hout + (size_t)N_ * 32;
  int tt = t & 127;
  int sn = tt >> 3;        // node slot 0..15
  int sc = tt & 7;         // float4 column 0..7 within 32 floats
  for (int tile = blockIdx.x; tile < nTiles; tile += gridDim.x) {
    int base = tile * TILE;
    {
      int n = base + sn;
      float4 v = make_float4(0.f, 0.f, 0.f, 0.f);
      if (n < N_) {
        if (t < 128) {
          float r = redshift[n];
#pragma unroll
          for (int jj = 0; jj < 4; ++jj) {
            int j = sc * 4 + jj;
            (&v.x)[jj] = fmaxf(fmaf(r, esw[j], esb[j]), 0.0f);
          }
          *reinterpret_cast<float4*>(hout + (size_t)n * 32 + sc * 4) = v;
        } else {
          float x0 = shapes[n * 2 + 0];
          float x1 = shapes[n * 2 + 1];
#pragma unroll
          for (int jj = 0; jj < 4; ++jj) {
            int j = sc * 4 + jj;
            (&v.x)[jj] = fmaf(x0, evw[j * 2 + 0], x1 * evw[j * 2 + 1]);
          }
          *reinterpret_cast<float4*>(hvbase + (size_t)n * 32 + sc * 4) = v;
        }
      }
      *reinterpret_cast<float4*>(&hsh[sn][(t < 128 ? 0 : 32) + sc * 4]) = v;
    }
    __syncthreads();
#pragma unroll
    for (int q = 0; q < 4; ++q) {
      int r = wib + q * 4;
      int n = base + r;
      if (n < N_) {
        const float4* ha = reinterpret_cast<const float4*>(hsh[r]);
        float ps0 = 0.f, ps1 = 0.f, ps2 = 0.f, ps3 = 0.f, pd0 = 0.f, pd1 = 0.f;
#pragma unroll
        for (int k4 = 0; k4 < 8; ++k4) {
          float4 a = ha[k4];
          float4 v = ha[8 + k4];
          int k = k4 * 4;
          ps0 = fmaf(a.x, ws_[k], ps0);     pd0 = fmaf(a.x, wd_[k], pd0);
          ps1 = fmaf(a.y, ws_[k + 1], ps1); pd1 = fmaf(a.y, wd_[k + 1], pd1);
          ps2 = fmaf(a.z, ws_[k + 2], ps2); pd0 = fmaf(a.z, wd_[k + 2], pd0);
          ps3 = fmaf(a.w, ws_[k + 3], ps3); pd1 = fmaf(a.w, wd_[k + 3], pd1);
          ps0 = fmaf(v.x, wv_[k], ps0);
          ps1 = fmaf(v.y, wv_[k + 1], ps1);
          ps2 = fmaf(v.z, wv_[k + 2], ps2);
          ps3 = fmaf(v.w, wv_[k + 3], ps3);
        }
        PSh[(size_t)n * 64 + lane] = f2bf((ps0 + ps1) + (ps2 + ps3));
        PDBh[(size_t)n * 64 + lane] = f2bf((pd0 + pd1) + bb1);
        H[(size_t)n * 64 + lane] = 0.0f;
      }
    }
    __syncthreads();
  }
}

// ---------------------------------------------------------------------------
// Edge phase: one wave per 64-edge chunk. 4-deep software pipeline: 32 PS
// gathers in flight; a batch is issued ~3 consume-phases (~670 cyc) before
// its use -> covers L3 latency. Segment-boundary PDB values prefetched a
// full segment ahead. Dual accumulators.
// ---------------------------------------------------------------------------
#define ISSUE(P, G)                                             \
  do {                                                          \
    int t0 = __builtin_amdgcn_readlane(sv, (G) + 0);            \
    int t1 = __builtin_amdgcn_readlane(sv, (G) + 1);            \
    int t2 = __builtin_amdgcn_readlane(sv, (G) + 2);            \
    int t3 = __builtin_amdgcn_readlane(sv, (G) + 3);            \
    int t4 = __builtin_amdgcn_readlane(sv, (G) + 4);            \
    int t5 = __builtin_amdgcn_readlane(sv, (G) + 5);            \
    int t6 = __builtin_amdgcn_readlane(sv, (G) + 6);            \
    int t7 = __builtin_amdgcn_readlane(sv, (G) + 7);            \
    P##0 = PSh[(size_t)t0 * 64 + lane];                         \
    P##1 = PSh[(size_t)t1 * 64 + lane];                         \
    P##2 = PSh[(size_t)t2 * 64 + lane];                         \
    P##3 = PSh[(size_t)t3 * 64 + lane];                         \
    P##4 = PSh[(size_t)t4 * 64 + lane];                         \
    P##5 = PSh[(size_t)t5 * 64 + lane];                         \
    P##6 = PSh[(size_t)t6 * 64 + lane];                         \
    P##7 = PSh[(size_t)t7 * 64 + lane];                         \
  } while (0)

#define FLUSH()                                                          \
  do {                                                                   \
    atomicAdd(H + (size_t)dcur * 64 + lane, acc0 + acc1);                \
    acc0 = acc1 = 0.0f;                                                  \
    dcur = dnext;                                                        \
    pdj = pdj_next;                                                      \
    bmask &= bmask - 1;                                                  \
    bnext = bmask ? (int)__builtin_ctzll(bmask) : 64;                    \
    dnext = (bnext < 64) ? __builtin_amdgcn_readlane(dv, bnext) : dcur;  \
    pdj_next = bf2f(PDBh[(size_t)dnext * 64 + lane]);                    \
  } while (0)

#define EDGE_ONE(PSV, E)                                                     \
  do {                                                                       \
    if ((E) == bnext) FLUSH();                                               \
    float psv = bf2f((ushort_t)(PSV));                                       \
    float di = readlane_f(ed.x, (E));                                        \
    uint_t pk = (uint_t)__builtin_amdgcn_readlane(__float_as_int(ed.y), (E));\
    float c2 = __uint_as_float(pk << 16);                                    \
    float s2 = __uint_as_float(pk & 0xFFFF0000u);                            \
    float pre = fmaf(wg0, di, fmaf(wg1, c2, fmaf(wg2, s2, psv + pdj)));      \
    if ((E) & 1) acc1 += silu_f(pre); else acc0 += silu_f(pre);              \
  } while (0)

#define CONSUME(P, G)                                            \
  do {                                                           \
    EDGE_ONE(P##0, (G) + 0); EDGE_ONE(P##1, (G) + 1);            \
    EDGE_ONE(P##2, (G) + 2); EDGE_ONE(P##3, (G) + 3);            \
    EDGE_ONE(P##4, (G) + 4); EDGE_ONE(P##5, (G) + 5);            \
    EDGE_ONE(P##6, (G) + 6); EDGE_ONE(P##7, (G) + 7);            \
  } while (0)

__global__ __launch_bounds__(256) void edge_kernel(
    const ushort_t* __restrict__ PSh, const ushort_t* __restrict__ PDBh,
    const float4* __restrict__ edata,
    const float* __restrict__ W1l, float* __restrict__ H, int nchunk) {
  int lane = threadIdx.x & 63, wib = threadIdx.x >> 6;
  int chunk = blockIdx.x * WPB + wib;
  if (chunk >= nchunk) return;
  int base = chunk << 6;
  float wg0 = W1l[lane * 99 + 96];
  float wg1 = W1l[lane * 99 + 97];
  float wg2 = W1l[lane * 99 + 98];
  float4 ed = edata[base + lane];  // x=dist, y=[s2|c2]bf16, z=src, w=dst
  int sv = __float_as_int(ed.z);
  int dv = __float_as_int(ed.w);
  int dprev = __shfl_up(dv, 1);
  unsigned long long bmask = __ballot(dv != dprev) & ~1ull;
  int dcur = rfl(dv);
  float pdj = bf2f(PDBh[(size_t)dcur * 64 + lane]);
  int bnext = bmask ? (int)__builtin_ctzll(bmask) : 64;
  int dnext = (bnext < 64) ? __builtin_amdgcn_readlane(dv, bnext) : dcur;
  float pdj_next = bf2f(PDBh[(size_t)dnext * 64 + lane]);
  float acc0 = 0.0f, acc1 = 0.0f;
  uint_t pA0, pA1, pA2, pA3, pA4, pA5, pA6, pA7;
  uint_t pB0, pB1, pB2, pB3, pB4, pB5, pB6, pB7;
  uint_t pC0, pC1, pC2, pC3, pC4, pC5, pC6, pC7;
  uint_t pD0, pD1, pD2, pD3, pD4, pD5, pD6, pD7;
  ISSUE(pA, 0);
  ISSUE(pB, 8);
  ISSUE(pC, 16);
  ISSUE(pD, 24);
  CONSUME(pA, 0);
  ISSUE(pA, 32);
  CONSUME(pB, 8);
  ISSUE(pB, 40);
  CONSUME(pC, 16);
  ISSUE(pC, 48);
  CONSUME(pD, 24);
  ISSUE(pD, 56);
  CONSUME(pA, 32);
  CONSUME(pB, 40);
  CONSUME(pC, 48);
  CONSUME(pD, 56);
  atomicAdd(H + (size_t)dcur * 64 + lane, acc0 + acc1);
}

// ---------------------------------------------------------------------------
// Fused node update + next-layer projection:
//   hnew[n] = h[n] + W2.H[n] + deg(n)*b2   -> hout (and kept in LDS)
//   PS/PDB(next layer) from hnew; H zeroed for next layer.
// ---------------------------------------------------------------------------
__global__ __launch_bounds__(256) void updproj_kernel(
    float* __restrict__ hout, float* __restrict__ H,
    const int* __restrict__ deg,
    const float* __restrict__ W2l, const float* __restrict__ b2l,
    const float* __restrict__ W1n, const float* __restrict__ b1n,
    ushort_t* __restrict__ PSh, ushort_t* __restrict__ PDBh, int N_) {
  __shared__ float w2sh[64 * 65];
  __shared__ float wsh[99 * 64];
  __shared__ __align__(16) float Hsh[TILE][64];
  int t = threadIdx.x;
  for (int i = t; i < 64 * 64; i += 256) w2sh[(i >> 6) * 65 + (i & 63)] = W2l[i];
  for (int i = t; i < 99 * 64; i += 256) wsh[i] = W1n[i];
  __syncthreads();
  int lane = t & 63, wib = t >> 6;
  float w2[64];
#pragma unroll
  for (int k = 0; k < 64; ++k) w2[k] = w2sh[lane * 65 + k];
  float ws_[32], wd_[32], wv_[32];
#pragma unroll
  for (int k = 0; k < 32; ++k) {
    ws_[k] = wsh[lane * 99 + k];
    wd_[k] = wsh[lane * 99 + 32 + k];
    wv_[k] = wsh[lane * 99 + 64 + k];
  }
  float bb2 = b2l[lane];
  float bb1 = b1n[lane];
  const int nTiles = (N_ + TILE - 1) / TILE;
  size_t plane = (size_t)(lane >> 5) * ((size_t)N_ * 32);
  int sn = t >> 4;   // node slot 0..15
  int sc = t & 15;   // float4 column 0..15 within 64 floats
  for (int tile = blockIdx.x; tile < nTiles; tile += gridDim.x) {
    int base = tile * TILE;
    {
      int n = base + sn;
      float4 v = (n < N_) ? *reinterpret_cast<const float4*>(H + (size_t)n * 64 + sc * 4)
                          : make_float4(0.f, 0.f, 0.f, 0.f);
      *reinterpret_cast<float4*>(&Hsh[sn][sc * 4]) = v;
    }
    __syncthreads();
#pragma unroll
    for (int q = 0; q < 4; ++q) {
      int r = wib + q * 4;
      int n = base + r;
      if (n < N_) {
        const float4* hm = reinterpret_cast<const float4*>(Hsh[r]);
        float o0 = 0.f, o1 = 0.f;
#pragma unroll
        for (int k4 = 0; k4 < 16; k4 += 2) {
          float4 m0 = hm[k4];
          float4 m1 = hm[k4 + 1];
          o0 = fmaf(m0.x, w2[k4 * 4 + 0], o0);
          o0 = fmaf(m0.y, w2[k4 * 4 + 1], o0);
          o0 = fmaf(m0.z, w2[k4 * 4 + 2], o0);
          o0 = fmaf(m0.w, w2[k4 * 4 + 3], o0);
          o1 = fmaf(m1.x, w2[k4 * 4 + 4], o1);
          o1 = fmaf(m1.y, w2[k4 * 4 + 5], o1);
          o1 = fmaf(m1.z, w2[k4 * 4 + 6], o1);
          o1 = fmaf(m1.w, w2[k4 * 4 + 7], o1);
        }
        float degf = (float)deg[n];
        size_t idx = plane + (size_t)n * 32 + (lane & 31);
        float hnew = hout[idx] + (o0 + o1) + degf * bb2;
        hout[idx] = hnew;
        Hsh[r][lane] = hnew;
        asm volatile("s_waitcnt lgkmcnt(0)" ::: "memory");
        const float4* ha = reinterpret_cast<const float4*>(Hsh[r]);
        float ps0 = 0.f, ps1 = 0.f, ps2 = 0.f, ps3 = 0.f, pd0 = 0.f, pd1 = 0.f;
#pragma unroll
        for (int k4 = 0; k4 < 8; ++k4) {
          float4 a = ha[k4];
          float4 v = ha[8 + k4];
          int k = k4 * 4;
          ps0 = fmaf(a.x, ws_[k], ps0);     pd0 = fmaf(a.x, wd_[k], pd0);
          ps1 = fmaf(a.y, ws_[k + 1], ps1); pd1 = fmaf(a.y, wd_[k + 1], pd1);
          ps2 = fmaf(a.z, ws_[k + 2], ps2); pd0 = fmaf(a.z, wd_[k + 2], pd0);
          ps3 = fmaf(a.w, ws_[k + 3], ps3); pd1 = fmaf(a.w, wd_[k + 3], pd1);
          ps0 = fmaf(v.x, wv_[k], ps0);
          ps1 = fmaf(v.y, wv_[k + 1], ps1);
          ps2 = fmaf(v.z, wv_[k + 2], ps2);
          ps3 = fmaf(v.w, wv_[k + 3], ps3);
        }
        PSh[(size_t)n * 64 + lane] = f2bf((ps0 + ps1) + (ps2 + ps3));
        PDBh[(size_t)n * 64 + lane] = f2bf((pd0 + pd1) + bb1);
        H[(size_t)n * 64 + lane] = 0.0f;
      }
    }
    __syncthreads();
  }
}

// ---------------------------------------------------------------------------
// Final node update (last layer): h[n,:] += W2 . H[n,:] + deg(n)*b2
// ---------------------------------------------------------------------------
__global__ __launch_bounds__(256) void out_kernel(
    float* __restrict__ hout, const float* __restrict__ H,
    const int* __restrict__ deg,
    const float* __restrict__ W2l, const float* __restrict__ b2l, int N_) {
  __shared__ float w2sh[64 * 65];
  __shared__ __align__(16) float Hsh[TILE][64];
  int t = threadIdx.x;
  for (int i = t; i < 64 * 64; i += 256) w2sh[(i >> 6) * 65 + (i & 63)] = W2l[i];
  __syncthreads();
  int lane = t & 63, wib = t >> 6;
  float w2[64];
#pragma unroll
  for (int k = 0; k < 64; ++k) w2[k] = w2sh[lane * 65 + k];
  float bb2 = b2l[lane];
  const int nTiles = (N_ + TILE - 1) / TILE;
  size_t plane = (size_t)(lane >> 5) * ((size_t)N_ * 32);
  int sn = t >> 4;
  int sc = t & 15;
  for (int tile = blockIdx.x; tile < nTiles; tile += gridDim.x) {
    int base = tile * TILE;
    {
      int n = base + sn;
      float4 v = (n < N_) ? *reinterpret_cast<const float4*>(H + (size_t)n * 64 + sc * 4)
                          : make_float4(0.f, 0.f, 0.f, 0.f);
      *reinterpret_cast<float4*>(&Hsh[sn][sc * 4]) = v;
    }
    __syncthreads();
#pragma unroll
    for (int q = 0; q < 4; ++q) {
      int r = wib + q * 4;
      int n = base + r;
      if (n < N_) {
        const float4* hm = reinterpret_cast<const float4*>(Hsh[r]);
        float o0 = 0.f, o1 = 0.f;
#pragma unroll
        for (int k4 = 0; k4 < 16; k4 += 2) {
          float4 m0 = hm[k4];
          float4 m1 = hm[k4 + 1];
          o0 = fmaf(m0.x, w2[k4 * 4 + 0], o0);
          o0 = fmaf(m0.y, w2[k4 * 4 + 1], o0);
          o0 = fmaf(m0.z, w2[k4 * 4 + 2], o0);
          o0 = fmaf(m0.w, w2[k4 * 4 + 3], o0);
          o1 = fmaf(m1.x, w2[k4 * 4 + 4], o1);
          o1 = fmaf(m1.y, w2[k4 * 4 + 5], o1);
          o1 = fmaf(m1.z, w2[k4 * 4 + 6], o1);
          o1 = fmaf(m1.w, w2[k4 * 4 + 7], o1);
        }
        float degf = (float)deg[n];
        size_t idx = plane + (size_t)n * 32 + (lane & 31);
        hout[idx] += (o0 + o1) + degf * bb2;
      }
    }
    __syncthreads();
  }
}

extern "C" void kernel_launch(void* const* d_in, const int* in_sizes, int n_in,
                              void* d_out, int out_size, void* d_ws, size_t ws_size,
                              hipStream_t stream) {
  const float* pos      = (const float*)d_in[0];
  const float* redshift = (const float*)d_in[1];
  const float* shapes   = (const float*)d_in[2];
  const int*   ei       = (const int*)d_in[3];
  const float* enc_s_w  = (const float*)d_in[4];
  const float* enc_s_b  = (const float*)d_in[5];
  const float* enc_v_w  = (const float*)d_in[6];
  const float* W1       = (const float*)d_in[7];
  const float* b1       = (const float*)d_in[8];
  const float* W2       = (const float*)d_in[9];
  const float* b2       = (const float*)d_in[10];

  const int N_ = in_sizes[1];      // 50000
  const int E_ = in_sizes[3] / 2;  // 1000000
  const int nchunk = (E_ + 63) / 64;
  const int padE = nchunk * 64;

  // Workspace (~42 MB): edata first (16B alignment from d_ws base)
  float4*   edata = (float4*)d_ws;                          // padE
  float*    H     = (float*)(edata + padE);                 // (N+1)*64 f32
  ushort_t* PSh   = (ushort_t*)(H + (size_t)(N_ + 1) * 64); // N*64 bf16
  ushort_t* PDBh  = PSh + (size_t)N_ * 64;                  // (N+1)*64 bf16
  int* rowptr = (int*)(PDBh + (size_t)(N_ + 1) * 64);       // N+1
  int* deg    = rowptr + (N_ + 1);                          // N
  int* cursor = deg + N_;                                   // N (adjacent)
  int* bsum   = cursor + N_;                                // 1024

  float* hout = (float*)d_out;  // planar h lives in d_out

  // CSR build + layer-invariant geometry (once)
  zero_kernel<<<dim3((2 * N_ + 255) / 256), dim3(256), 0, stream>>>(deg, 2 * N_);
  deg_kernel<<<dim3((E_ + 255) / 256), dim3(256), 0, stream>>>(ei, deg, E_);
  const int nbA = (N_ + 1023) / 1024;
  scanA_kernel<<<dim3(nbA), dim3(1024), 0, stream>>>(deg, rowptr, bsum, N_);
  scanB_kernel<<<dim3(1), dim3(1024), 0, stream>>>(bsum, nbA);
  scanC_kernel<<<dim3((N_ + 255) / 256), dim3(256), 0, stream>>>(rowptr, bsum, N_);
  scatter_kernel<<<dim3((padE + 255) / 256), dim3(256), 0, stream>>>(
      ei, pos, rowptr, cursor, edata, E_, padE, N_);

  const int edgeBlocks = (nchunk + WPB - 1) / WPB;

  // fused encode + layer-0 projections
  encpsd_kernel<<<dim3(1024), dim3(256), 0, stream>>>(
      redshift, shapes, enc_s_w, enc_s_b, enc_v_w,
      hout, W1, b1, PSh, PDBh, H, N_);

  for (int l = 0; l < 3; ++l) {
    const float* W2l = W2 + (size_t)l * 64 * 64;
    const float* b2l = b2 + (size_t)l * 64;
    edge_kernel<<<dim3(edgeBlocks), dim3(256), 0, stream>>>(
        PSh, PDBh, edata, W1 + (size_t)l * 64 * 99, H, nchunk);
    if (l < 2) {
      updproj_kernel<<<dim3(1024), dim3(256), 0, stream>>>(
          hout, H, deg, W2l, b2l,
          W1 + (size_t)(l + 1) * 64 * 99, b1 + (size_t)(l + 1) * 64,
          PSh, PDBh, N_);
    } else {
      out_kernel<<<dim3(1024), dim3(256), 0, stream>>>(
          hout, H, deg, W2l, b2l, N_);
    }
  }
}